// Round 8
// baseline (295.969 us; speedup 1.0000x reference)
//
#include <hip/hip_runtime.h>
#include <hip/hip_bf16.h>

#define N 768
#define IN_DIM 128
#define HID 256
#define HD 32
#define TJ 64
#define NT (N / TJ)
#define SCALE_INV 0.17677669529663687f  // 1/sqrt(32)

typedef short s16x8 __attribute__((ext_vector_type(8)));
typedef float f32x4 __attribute__((ext_vector_type(4)));

__device__ __forceinline__ unsigned short bf_bits(float f) {
    __hip_bfloat16 h = __float2bfloat16(f);
    union { __hip_bfloat16 h; unsigned short u; } c; c.h = h; return c.u;
}
__device__ __forceinline__ unsigned cvt2(float a, float b) {
    __hip_bfloat162 h2 = __float22bfloat162_rn(make_float2(a, b));
    union { __hip_bfloat162 h; unsigned u; } c; c.h = h2; return c.u;
}

// LDS-only barrier: waits own-wave LDS ops, leaves global loads in flight.
#define BAR_LDS() do { asm volatile("s_waitcnt lgkmcnt(0)" ::: "memory"); \
                       __builtin_amdgcn_s_barrier(); } while (0)

// ---------------------------------------------------------------------------
// kernel 1 (grid 1024):
//  blocks 0..767   : per-i prep -> Q f32; Vt = V^T f32; A = pos@W1 f32;
//                    Kt = K^T f32; w3q fragments for row i
//  blocks 768..1023: pack W2^T into MFMA A-frag order + transpose Wo
// ---------------------------------------------------------------------------
__global__ __launch_bounds__(256) void prep_kernel(
    const float* __restrict__ x, const float* __restrict__ pos,
    const float* __restrict__ Wq, const float* __restrict__ bq,
    const float* __restrict__ Wk, const float* __restrict__ bk,
    const float* __restrict__ Wv, const float* __restrict__ bv,
    const float* __restrict__ W1, const float* __restrict__ W2,
    const float* __restrict__ W3, const float* __restrict__ Wo,
    float* __restrict__ Q, float* __restrict__ Kt,
    float* __restrict__ Vt, float* __restrict__ A,
    unsigned short* __restrict__ w2tf, float* __restrict__ WoT,
    unsigned short* __restrict__ w3qg)
{
    const int bx = blockIdx.x, t = threadIdx.x;
    __shared__ float xs[IN_DIM];
    __shared__ float ps[3];
    __shared__ float qrow[HID];

    if (bx >= N) {
        // pack W2^T frags: w2tf[((kt*8+s)*64+l)*8+e] = W2[32s+8(l>>4)+e][16kt+(l&15)]
        const int p = (bx - N) * 256 + t;               // 0..65535
        const int e = p & 7, l = (p >> 3) & 63, s = (p >> 9) & 7, kt = p >> 12;
        const int krow = 32 * s + 8 * (l >> 4) + e;     // contraction index
        const int kcol = 16 * kt + (l & 15);            // output k index
        w2tf[p] = bf_bits(W2[krow * HID + kcol]);
        WoT[p] = Wo[(p & 255) * HID + (p >> 8)];        // WoT[t][k] = Wo[k][t]
        return;
    }

    const int i = bx;
    if (t < IN_DIM) xs[t] = x[i * IN_DIM + t];
    if (t < 3) ps[t] = pos[i * 3 + t];
    __syncthreads();
    float q = bq[t], k = bk[t], v = bv[t];
#pragma unroll 8
    for (int kk = 0; kk < IN_DIM; ++kk) {
        const float xv = xs[kk];
        q += xv * Wq[kk * HID + t];
        k += xv * Wk[kk * HID + t];
        v += xv * Wv[kk * HID + t];
    }
    const float a = ps[0] * W1[t] + ps[1] * W1[HID + t] + ps[2] * W1[2 * HID + t];
    Q[i * HID + t] = q;
    Kt[(size_t)t * N + i] = k;
    Vt[(size_t)t * N + i] = v;
    A[i * HID + t] = a;
    qrow[t] = q;
    __syncthreads();

    // w3q frags: w3q[h][k] = sum_d W3[k][d]*q[h*32+d], B-frag order
    const int l = t & 63, sp = t >> 6, lg = l >> 4, hh = l & 15;
#pragma unroll
    for (int ss = 0; ss < 2; ++ss) {
        const int s = 2 * sp + ss;
        s16x8 frag = {0, 0, 0, 0, 0, 0, 0, 0};
        if (hh < 8) {
#pragma unroll
            for (int e = 0; e < 8; ++e) {
                const int kk = 32 * s + 8 * lg + e;
                const float* w3p = W3 + kk * HD;
                float acc = 0.f;
#pragma unroll
                for (int d0 = 0; d0 < 32; d0 += 4) {
                    const float4 wv = *(const float4*)(w3p + d0);
                    acc += wv.x * qrow[hh * HD + d0] + wv.y * qrow[hh * HD + d0 + 1]
                         + wv.z * qrow[hh * HD + d0 + 2] + wv.w * qrow[hh * HD + d0 + 3];
                }
                frag[e] = (short)bf_bits(acc);
            }
        }
        *(s16x8*)(w3qg + (size_t)i * 4096 + (size_t)(s * 64 + l) * 8) = frag;
    }
}

// ---------------------------------------------------------------------------
// kernel 2: S1[h][i][j] = q_i,h . k_j,h (f32). 32 i x 64 j x 8 h per block.
// ---------------------------------------------------------------------------
__global__ __launch_bounds__(256) void s1_kernel(
    const float* __restrict__ Q, const float* __restrict__ Kt,
    float* __restrict__ S1)
{
    const int t = threadIdx.x;
    const int i0 = (blockIdx.x / 12) * 32;
    const int j0 = (blockIdx.x % 12) * 64;
    __shared__ float qTs[256 * 36];   // [d'][i], row stride 36, XOR-swizzled chunks

    {
        const int iq = t & 31;
        const int dbase = (t >> 5) * 32;
        const int xk = t >> 5;
        const int colsw = (((iq >> 2) ^ xk) << 2) + (iq & 3);
        const float* qp = Q + (size_t)(i0 + iq) * HID + dbase;
#pragma unroll
        for (int cc = 0; cc < 8; ++cc) {
            const float4 qv = *(const float4*)(qp + 4 * cc);
            qTs[(dbase + 4 * cc + 0) * 36 + colsw] = qv.x;
            qTs[(dbase + 4 * cc + 1) * 36 + colsw] = qv.y;
            qTs[(dbase + 4 * cc + 2) * 36 + colsw] = qv.z;
            qTs[(dbase + 4 * cc + 3) * 36 + colsw] = qv.w;
        }
    }
    __syncthreads();

    const int h = t >> 5, jj = t & 31;
    const int j1 = j0 + jj, j2 = j0 + jj + 32;
    f32x4 acc0[8] = {}, acc1[8] = {};
    const float* kp = Kt + (size_t)(32 * h) * N + j1;
#pragma unroll 4
    for (int d = 0; d < 32; ++d) {
        const float k0 = kp[(size_t)d * N];
        const float k1 = kp[(size_t)d * N + 32];
        const float* qrow = &qTs[(32 * h + d) * 36];
#pragma unroll
        for (int ic = 0; ic < 8; ++ic) {
            const f32x4 qv = *(const f32x4*)&qrow[(ic ^ h) << 2];
            acc0[ic] += qv * k0;
            acc1[ic] += qv * k1;
        }
    }
    float* op = S1 + (size_t)h * (N * N) + (size_t)i0 * N;
#pragma unroll
    for (int ic = 0; ic < 8; ++ic)
#pragma unroll
        for (int u = 0; u < 4; ++u) {
            op[(size_t)(4 * ic + u) * N + j1] = acc0[ic][u];
            op[(size_t)(4 * ic + u) * N + j2] = acc1[ic][u];
        }
}

// ---------------------------------------------------------------------------
// kernel 3: fused main, one block (8 waves, 512 thr) per query row i,
// 2 blocks/CU. 3 LDS-only barriers/tile (global loads stay in flight).
// ---------------------------------------------------------------------------
__global__ __launch_bounds__(512, 4) void fused_main_kernel(
    const float* __restrict__ Ag, const float* __restrict__ S1,
    const float* __restrict__ Vt,
    const unsigned short* __restrict__ w2tf, const unsigned short* __restrict__ w3qg,
    const float* __restrict__ b1, const float* __restrict__ b2,
    const float* __restrict__ WoT, const float* __restrict__ bo,
    float* __restrict__ out)
{
    const int i = blockIdx.x, t = threadIdx.x;
    const int w = t >> 6, l = t & 63;
    const int lg = l >> 4, l15 = l & 15;

    __shared__ __align__(16) short h1f[4 * 8 * 64 * 8];   // 32 KB  H1 B-frags
    __shared__ __align__(16) short h2s[64 * 264];          // 33.8 KB H2 [j][k]
    __shared__ __align__(16) short w3qf[8 * 64 * 8];       // 8 KB   w3q B-frags
    __shared__ __align__(16) float slds[8 * 68];           // scores [h][jj]
    __shared__ __align__(16) float plds[8 * 68];           // probs  [h][jj]
    float* const oa = slds;                                // epilogue overlay

    // ---------------- prolog (all per-thread state in registers)
    *(s16x8*)&w3qf[t * 8] = *(const s16x8*)(w3qg + (size_t)i * 4096 + (size_t)t * 8);

    const int c0 = 32 * w + 8 * lg;                        // this thread's k-slice
    float4 base0, base1;                                    // b1 - A[i], slice
    {
        const float4 b1a = *(const float4*)(b1 + c0);
        const float4 b1b = *(const float4*)(b1 + c0 + 4);
        const float4 aia = *(const float4*)(Ag + (size_t)i * HID + c0);
        const float4 aib = *(const float4*)(Ag + (size_t)i * HID + c0 + 4);
        base0 = make_float4(b1a.x - aia.x, b1a.y - aia.y, b1a.z - aia.z, b1a.w - aia.w);
        base1 = make_float4(b1b.x - aib.x, b1b.y - aib.y, b1b.z - aib.z, b1b.w - aib.w);
    }
    const float4 bias0 = *(const float4*)(b2 + 32 * w + 4 * lg);
    const float4 bias1 = *(const float4*)(b2 + 32 * w + 16 + 4 * lg);

    float pv = 0.f, psum = 0.f, mr = -3.0e38f;
    const int d31 = l & 31, jh = l >> 5;
    BAR_LDS();   // w3qf ready

#pragma unroll 1
    for (int tile = 0; tile < NT; ++tile) {
        const int j0 = tile * TJ;

        // ---- issue W2^T A-frag loads first (hidden under phase-A VALU)
        s16x8 bfr[16];
#pragma unroll
        for (int s = 0; s < 8; ++s)
#pragma unroll
            for (int kk = 0; kk < 2; ++kk)
                bfr[s * 2 + kk] = *(const s16x8*)(w2tf +
                    (size_t)((((2 * w + kk) * 8 + s) * 64 + l)) * 8);
        // S1 tile issued early (phase-C consumers only)
        float4 s1v = make_float4(0.f, 0.f, 0.f, 0.f);
        if (w < 4 && l15 < 8)
            s1v = *(const float4*)(S1 + (size_t)l15 * (N * N) + (size_t)i * N
                                   + j0 + 16 * w + 4 * lg);

        // ---- phase A: wave w produces s-slice w of H1 B-frags (all jjb)
        {
            const float* ap = Ag + (size_t)(j0 + l15) * HID + c0;
#pragma unroll
            for (int jjb = 0; jjb < 4; ++jjb) {
                const float4 a0 = *(const float4*)(ap + jjb * 16 * HID);
                const float4 a1 = *(const float4*)(ap + jjb * 16 * HID + 4);
                uint4 hv;
                hv.x = cvt2(fmaxf(a0.x + base0.x, 0.f), fmaxf(a0.y + base0.y, 0.f));
                hv.y = cvt2(fmaxf(a0.z + base0.z, 0.f), fmaxf(a0.w + base0.w, 0.f));
                hv.z = cvt2(fmaxf(a1.x + base1.x, 0.f), fmaxf(a1.y + base1.y, 0.f));
                hv.w = cvt2(fmaxf(a1.z + base1.z, 0.f), fmaxf(a1.w + base1.w, 0.f));
                *(uint4*)&h1f[((jjb * 8 + w) * 64 + l) * 8] = hv;
            }
        }
        BAR_LDS();   // bar1: h1f ready (bfr/S1 loads remain in flight)

        // ---- phase B: 64 MFMA/wave; H2 packed b64 stores
#pragma unroll
        for (int jjb = 0; jjb < 4; ++jjb) {
            f32x4 acc0 = {}, acc1 = {};
#pragma unroll
            for (int s = 0; s < 8; ++s) {
                const s16x8 bfrag = *(const s16x8*)&h1f[((jjb * 8 + s) * 64 + l) * 8];
                acc0 = __builtin_amdgcn_mfma_f32_16x16x32_bf16(bfr[s * 2 + 0], bfrag, acc0, 0, 0, 0);
                acc1 = __builtin_amdgcn_mfma_f32_16x16x32_bf16(bfr[s * 2 + 1], bfrag, acc1, 0, 0, 0);
            }
            const int rb = (16 * jjb + l15) * 264 + 32 * w + 4 * lg;
            uint2 pw;
            pw.x = cvt2(fmaxf(acc0[0] + bias0.x, 0.f), fmaxf(acc0[1] + bias0.y, 0.f));
            pw.y = cvt2(fmaxf(acc0[2] + bias0.z, 0.f), fmaxf(acc0[3] + bias0.w, 0.f));
            *(uint2*)&h2s[rb] = pw;
            pw.x = cvt2(fmaxf(acc1[0] + bias1.x, 0.f), fmaxf(acc1[1] + bias1.y, 0.f));
            pw.y = cvt2(fmaxf(acc1[2] + bias1.z, 0.f), fmaxf(acc1[3] + bias1.w, 0.f));
            *(uint2*)&h2s[rb + 16] = pw;
        }
        BAR_LDS();   // bar2: h2s ready

        // ---- issue V loads (consumed in PV after bar3; hidden under phase C)
        float4 vv[8];
        {
            const float* vp = Vt + (size_t)(32 * w + d31) * N + j0 + 32 * jh;
#pragma unroll
            for (int c = 0; c < 8; ++c) vv[c] = *(const float4*)(vp + 4 * c);
        }

        // ---- phase C (waves 0-3): score2 = H2 @ w3q; combine with fp32 S1
        if (w < 4) {
            f32x4 acc2 = {};
            const int rowc = (16 * w + l15) * 264;
#pragma unroll
            for (int s = 0; s < 8; ++s) {
                const s16x8 a2 = *(const s16x8*)&h2s[rowc + 32 * s + 8 * lg];
                const s16x8 wq = *(const s16x8*)&w3qf[(s * 64 + l) * 8];
                acc2 = __builtin_amdgcn_mfma_f32_16x16x32_bf16(a2, wq, acc2, 0, 0, 0);
            }
            if (l15 < 8) {
                float4 sc;
                sc.x = (acc2[0] + s1v.x) * SCALE_INV;
                sc.y = (acc2[1] + s1v.y) * SCALE_INV;
                sc.z = (acc2[2] + s1v.z) * SCALE_INV;
                sc.w = (acc2[3] + s1v.w) * SCALE_INV;
                *(float4*)&slds[l15 * 68 + 16 * w + 4 * lg] = sc;
            }
        }
        BAR_LDS();   // bar3: slds scores ready (V loads remain in flight)

        // ---- p-gen + PV: wave w owns head w (fully wave-local)
        {
            const float s0 = slds[w * 68 + l];
            float m0 = s0;
#pragma unroll
            for (int o = 1; o < 64; o <<= 1) m0 = fmaxf(m0, __shfl_xor(m0, o));
            const float nm = fmaxf(mr, m0);
            const float r = __expf(mr - nm);
            mr = nm;
            const float p = __expf(s0 - nm);
            psum = psum * r + p;
            plds[w * 68 + l] = p;
            asm volatile("s_waitcnt lgkmcnt(0)" ::: "memory");  // own-wave LDS fence
            pv *= r;
            const float* pp = &plds[w * 68 + 32 * jh];
#pragma unroll
            for (int c = 0; c < 8; ++c) {
                const float4 pa = *(const float4*)(pp + 4 * c);
                pv += pa.x * vv[c].x + pa.y * vv[c].y
                    + pa.z * vv[c].z + pa.w * vv[c].w;
            }
        }
        // no end-of-tile barrier: all cross-wave hazards are >=1 barrier away
    }

    // ---------------- epilogue
#pragma unroll
    for (int o = 1; o < 64; o <<= 1) psum += __shfl_xor(psum, o);
    pv += __shfl_xor(pv, 32);          // combine j-halves (same hid)
    const float ov = pv / psum;
    __syncthreads();                   // all slds reads done before overlay
    if (l < 32) oa[32 * w + l] = ov;
    __syncthreads();
    if (t < HID) {
        float r = bo[t];
        const float* wop = WoT + (size_t)t * HID;
#pragma unroll 4
        for (int k = 0; k < HID; k += 4) {
            const float4 ovv = *(const float4*)&oa[k];
            const float4 wv = *(const float4*)(wop + k);
            r += ovv.x * wv.x + ovv.y * wv.y + ovv.z * wv.z + ovv.w * wv.w;
        }
        out[(size_t)i * HID + t] = r;
    }
}

// ---------------------------------------------------------------------------
extern "C" void kernel_launch(void* const* d_in, const int* in_sizes, int n_in,
                              void* d_out, int out_size, void* d_ws, size_t ws_size,
                              hipStream_t stream)
{
    const float* x   = (const float*)d_in[0];
    const float* pos = (const float*)d_in[1];
    const float* Wq  = (const float*)d_in[2];
    const float* bq  = (const float*)d_in[3];
    const float* Wk  = (const float*)d_in[4];
    const float* bk  = (const float*)d_in[5];
    const float* Wv  = (const float*)d_in[6];
    const float* bv  = (const float*)d_in[7];
    const float* Wo  = (const float*)d_in[8];
    const float* bo  = (const float*)d_in[9];
    const float* W1  = (const float*)d_in[10];
    const float* b1  = (const float*)d_in[11];
    const float* W2  = (const float*)d_in[12];
    const float* b2  = (const float*)d_in[13];
    const float* W3  = (const float*)d_in[14];
    const float* b3  = (const float*)d_in[15];  // softmax-invariant, folded out
    (void)b3;
    float* out = (float*)d_out;

    char* ws = (char*)d_ws;
    float* Q  = (float*)(ws + 0);                            // 768*256 f32
    float* A  = (float*)(ws + 786432);                       // 768*256 f32
    float* Kt = (float*)(ws + 1572864);                      // 256*768 f32
    float* Vt = (float*)(ws + 2359296);                      // 256*768 f32
    float* S1 = (float*)(ws + 3145728);                      // 8*768*768 f32
    unsigned short* w2tf = (unsigned short*)(ws + 22020096); // 65536 bf16
    unsigned short* w3qg = (unsigned short*)(ws + 22151168); // 768*4096 bf16
    float* WoT = (float*)(ws + 28442624);                    // 256*256 f32

    prep_kernel<<<1024, 256, 0, stream>>>(x, pos, Wq, bq, Wk, bk, Wv, bv,
                                          W1, W2, W3, Wo,
                                          Q, Kt, Vt, A, w2tf, WoT, w3qg);
    s1_kernel<<<288, 256, 0, stream>>>(Q, Kt, S1);
    fused_main_kernel<<<N, 512, 0, stream>>>(A, S1, Vt, w2tf, w3qg,
                                             b1, b2, WoT, bo, out);
}

// Round 9
// 237.448 us; speedup vs baseline: 1.2465x; 1.2465x over previous
//
#include <hip/hip_runtime.h>
#include <hip/hip_bf16.h>

#define N 768
#define IN_DIM 128
#define HID 256
#define HD 32
#define TJ 64
#define NT (N / TJ)
#define SCALE_INV 0.17677669529663687f  // 1/sqrt(32)

typedef short s16x8 __attribute__((ext_vector_type(8)));
typedef float f32x4 __attribute__((ext_vector_type(4)));

__device__ __forceinline__ unsigned short bf_bits(float f) {
    __hip_bfloat16 h = __float2bfloat16(f);
    union { __hip_bfloat16 h; unsigned short u; } c; c.h = h; return c.u;
}
__device__ __forceinline__ unsigned cvt2(float a, float b) {
    __hip_bfloat162 h2 = __float22bfloat162_rn(make_float2(a, b));
    union { __hip_bfloat162 h; unsigned u; } c; c.h = h2; return c.u;
}

// LDS-only barrier: waits own-wave LDS ops, leaves global loads in flight.
#define BAR_LDS() do { asm volatile("s_waitcnt lgkmcnt(0)" ::: "memory"); \
                       __builtin_amdgcn_s_barrier(); } while (0)

// ---------------------------------------------------------------------------
// kernel 1 (grid 1024):
//  blocks 0..767   : per-i prep -> Q f32; Kt = K^T f32; Vt = V^T f32;
//                    A = pos@W1 f32; w3q fragments for row i
//  blocks 768..1023: pack W2^T into MFMA A-frag order + transpose Wo
// ---------------------------------------------------------------------------
__global__ __launch_bounds__(256) void prep_kernel(
    const float* __restrict__ x, const float* __restrict__ pos,
    const float* __restrict__ Wq, const float* __restrict__ bq,
    const float* __restrict__ Wk, const float* __restrict__ bk,
    const float* __restrict__ Wv, const float* __restrict__ bv,
    const float* __restrict__ W1, const float* __restrict__ W2,
    const float* __restrict__ W3, const float* __restrict__ Wo,
    float* __restrict__ Q, float* __restrict__ Kt,
    float* __restrict__ Vt, float* __restrict__ A,
    unsigned short* __restrict__ w2tf, float* __restrict__ WoT,
    unsigned short* __restrict__ w3qg)
{
    const int bx = blockIdx.x, t = threadIdx.x;
    __shared__ float xs[IN_DIM];
    __shared__ float ps[3];
    __shared__ float qrow[HID];

    if (bx >= N) {
        // pack W2^T frags: w2tf[((kt*8+s)*64+l)*8+e] = W2[32s+8(l>>4)+e][16kt+(l&15)]
        const int p = (bx - N) * 256 + t;               // 0..65535
        const int e = p & 7, l = (p >> 3) & 63, s = (p >> 9) & 7, kt = p >> 12;
        const int krow = 32 * s + 8 * (l >> 4) + e;     // contraction index
        const int kcol = 16 * kt + (l & 15);            // output k index
        w2tf[p] = bf_bits(W2[krow * HID + kcol]);
        WoT[p] = Wo[(p & 255) * HID + (p >> 8)];        // WoT[t][k] = Wo[k][t]
        return;
    }

    const int i = bx;
    if (t < IN_DIM) xs[t] = x[i * IN_DIM + t];
    if (t < 3) ps[t] = pos[i * 3 + t];
    __syncthreads();
    float q = bq[t], k = bk[t], v = bv[t];
#pragma unroll 8
    for (int kk = 0; kk < IN_DIM; ++kk) {
        const float xv = xs[kk];
        q += xv * Wq[kk * HID + t];
        k += xv * Wk[kk * HID + t];
        v += xv * Wv[kk * HID + t];
    }
    const float a = ps[0] * W1[t] + ps[1] * W1[HID + t] + ps[2] * W1[2 * HID + t];
    Q[i * HID + t] = q;
    Kt[(size_t)t * N + i] = k;
    Vt[(size_t)t * N + i] = v;
    A[i * HID + t] = a;
    qrow[t] = q;
    __syncthreads();

    // w3q frags: w3q[h][k] = sum_d W3[k][d]*q[h*32+d], B-frag order
    const int l = t & 63, sp = t >> 6, lg = l >> 4, hh = l & 15;
#pragma unroll
    for (int ss = 0; ss < 2; ++ss) {
        const int s = 2 * sp + ss;
        s16x8 frag = {0, 0, 0, 0, 0, 0, 0, 0};
        if (hh < 8) {
#pragma unroll
            for (int e = 0; e < 8; ++e) {
                const int kk = 32 * s + 8 * lg + e;
                const float* w3p = W3 + kk * HD;
                float acc = 0.f;
#pragma unroll
                for (int d0 = 0; d0 < 32; d0 += 4) {
                    const float4 wv = *(const float4*)(w3p + d0);
                    acc += wv.x * qrow[hh * HD + d0] + wv.y * qrow[hh * HD + d0 + 1]
                         + wv.z * qrow[hh * HD + d0 + 2] + wv.w * qrow[hh * HD + d0 + 3];
                }
                frag[e] = (short)bf_bits(acc);
            }
        }
        *(s16x8*)(w3qg + (size_t)i * 4096 + (size_t)(s * 64 + l) * 8) = frag;
    }
}

// ---------------------------------------------------------------------------
// kernel 2: S1[h][i][j] = q_i,h . k_j,h (f32). 32 i x 64 j x 8 h per block.
// ---------------------------------------------------------------------------
__global__ __launch_bounds__(256) void s1_kernel(
    const float* __restrict__ Q, const float* __restrict__ Kt,
    float* __restrict__ S1)
{
    const int t = threadIdx.x;
    const int i0 = (blockIdx.x / 12) * 32;
    const int j0 = (blockIdx.x % 12) * 64;
    __shared__ float qTs[256 * 36];   // [d'][i], row stride 36, XOR-swizzled chunks

    {
        const int iq = t & 31;
        const int dbase = (t >> 5) * 32;
        const int xk = t >> 5;
        const int colsw = (((iq >> 2) ^ xk) << 2) + (iq & 3);
        const float* qp = Q + (size_t)(i0 + iq) * HID + dbase;
#pragma unroll
        for (int cc = 0; cc < 8; ++cc) {
            const float4 qv = *(const float4*)(qp + 4 * cc);
            qTs[(dbase + 4 * cc + 0) * 36 + colsw] = qv.x;
            qTs[(dbase + 4 * cc + 1) * 36 + colsw] = qv.y;
            qTs[(dbase + 4 * cc + 2) * 36 + colsw] = qv.z;
            qTs[(dbase + 4 * cc + 3) * 36 + colsw] = qv.w;
        }
    }
    __syncthreads();

    const int h = t >> 5, jj = t & 31;
    const int j1 = j0 + jj, j2 = j0 + jj + 32;
    f32x4 acc0[8] = {}, acc1[8] = {};
    const float* kp = Kt + (size_t)(32 * h) * N + j1;
#pragma unroll 4
    for (int d = 0; d < 32; ++d) {
        const float k0 = kp[(size_t)d * N];
        const float k1 = kp[(size_t)d * N + 32];
        const float* qrow = &qTs[(32 * h + d) * 36];
#pragma unroll
        for (int ic = 0; ic < 8; ++ic) {
            const f32x4 qv = *(const f32x4*)&qrow[(ic ^ h) << 2];
            acc0[ic] += qv * k0;
            acc1[ic] += qv * k1;
        }
    }
    float* op = S1 + (size_t)h * (N * N) + (size_t)i0 * N;
#pragma unroll
    for (int ic = 0; ic < 8; ++ic)
#pragma unroll
        for (int u = 0; u < 4; ++u) {
            op[(size_t)(4 * ic + u) * N + j1] = acc0[ic][u];
            op[(size_t)(4 * ic + u) * N + j2] = acc1[ic][u];
        }
}

// ---------------------------------------------------------------------------
// kernel 3: fused main, one block (4 waves) per query row i, 2 blocks/CU.
// Round-6 structure; 3 LDS-only barriers/tile (global loads stay in flight).
// Wave w owns heads {2w, 2w+1} for softmax+PV (wave-local after bar3).
// ---------------------------------------------------------------------------
__global__ __launch_bounds__(256, 2) void fused_main_kernel(
    const float* __restrict__ Ag, const float* __restrict__ S1,
    const float* __restrict__ Vt,
    const unsigned short* __restrict__ w2tf, const unsigned short* __restrict__ w3qg,
    const float* __restrict__ b1, const float* __restrict__ b2,
    const float* __restrict__ WoT, const float* __restrict__ bo,
    float* __restrict__ out)
{
    const int i = blockIdx.x, t = threadIdx.x;
    const int w = t >> 6, l = t & 63;
    const int lg = l >> 4, l15 = l & 15;

    __shared__ __align__(16) short h1f[4 * 8 * 64 * 8];  // 32768 B  H1 B-frags
    __shared__ __align__(16) short h2s[64 * 264];         // 33792 B  H2 [j][k]
    __shared__ __align__(16) short w3qf[8 * 64 * 8];      // 8192 B   w3q B-frags
    __shared__ __align__(16) float slds[8 * 68];          // scores -> probs [h][jj]
    __shared__ float basek[HID];
    __shared__ float b2s[HID];
    float* const oa = slds;                               // epilogue overlay

    // ---------------- prolog
    basek[t] = b1[t] - Ag[(size_t)i * HID + t];
    b2s[t] = b2[t];
    {
        const int c0 = t, c1 = t + 256;
        *(s16x8*)&w3qf[c0 * 8] = *(const s16x8*)(w3qg + (size_t)i * 4096 + (size_t)c0 * 8);
        *(s16x8*)&w3qf[c1 * 8] = *(const s16x8*)(w3qg + (size_t)i * 4096 + (size_t)c1 * 8);
    }
    float pv = 0.f, psum0 = 0.f, psum1 = 0.f;
    float mr0 = -3.0e38f, mr1 = -3.0e38f;
    const int h = t >> 5;                 // PV head of this thread: 2w + (l>=32)
    __syncthreads();

#pragma unroll 1
    for (int tile = 0; tile < NT; ++tile) {
        const int j0 = tile * TJ;

        // ---- phase A: H1 = relu(A[j] - A[i] + b1) in B-fragment order
        const int jj = 16 * w + l15;
        const float* ap = Ag + (size_t)(j0 + jj) * HID + 8 * lg;
#pragma unroll
        for (int s = 0; s < 8; ++s) {
            const float4 a0 = *(const float4*)(ap + 32 * s);
            const float4 a1 = *(const float4*)(ap + 32 * s + 4);
            const float4 c0 = *(const float4*)&basek[32 * s + 8 * lg];
            const float4 c4 = *(const float4*)&basek[32 * s + 8 * lg + 4];
            uint4 hv;
            hv.x = cvt2(fmaxf(a0.x + c0.x, 0.f), fmaxf(a0.y + c0.y, 0.f));
            hv.y = cvt2(fmaxf(a0.z + c0.z, 0.f), fmaxf(a0.w + c0.w, 0.f));
            hv.z = cvt2(fmaxf(a1.x + c4.x, 0.f), fmaxf(a1.y + c4.y, 0.f));
            hv.w = cvt2(fmaxf(a1.z + c4.z, 0.f), fmaxf(a1.w + c4.w, 0.f));
            *(uint4*)&h1f[((w * 8 + s) * 64 + l) * 8] = hv;
        }
        // S1 tile (f32) issued early, consumed in phase C (stays in flight)
        float4 s1v = make_float4(0.f, 0.f, 0.f, 0.f);
        if (l15 < 8)
            s1v = *(const float4*)(S1 + (size_t)l15 * (N * N) + (size_t)i * N
                                   + j0 + 16 * w + 4 * lg);
        // W2^T A-frags for this wave's k-slice (per-tile lifetime)
        s16x8 bfr[32];
#pragma unroll
        for (int s = 0; s < 8; ++s)
#pragma unroll
            for (int ktl = 0; ktl < 4; ++ktl)
                bfr[s * 4 + ktl] = *(const s16x8*)(w2tf +
                    (size_t)((((4 * w + ktl) * 8 + s) * 64 + l)) * 8);
        BAR_LDS();   // bar1: h1f ready (bfr/S1 loads remain in flight)

        // ---- phase B: jjb-outer, acc[4] only (register-light, spill-free)
#pragma unroll
        for (int jjb = 0; jjb < 4; ++jjb) {
            f32x4 acc[4] = {};
#pragma unroll
            for (int s = 0; s < 8; ++s) {
                const s16x8 bfrag = *(const s16x8*)&h1f[((jjb * 8 + s) * 64 + l) * 8];
#pragma unroll
                for (int ktl = 0; ktl < 4; ++ktl)
                    acc[ktl] = __builtin_amdgcn_mfma_f32_16x16x32_bf16(
                        bfr[s * 4 + ktl], bfrag, acc[ktl], 0, 0, 0);
            }
            // epilogue: bias+relu, packed b64 stores h2s[j][k_out]
#pragma unroll
            for (int ktl = 0; ktl < 4; ++ktl) {
                const int k0 = 64 * w + 16 * ktl + 4 * lg;
                const float4 bv = *(const float4*)&b2s[k0];
                const f32x4 a = acc[ktl];
                uint2 pw;
                pw.x = cvt2(fmaxf(a[0] + bv.x, 0.f), fmaxf(a[1] + bv.y, 0.f));
                pw.y = cvt2(fmaxf(a[2] + bv.z, 0.f), fmaxf(a[3] + bv.w, 0.f));
                *(uint2*)&h2s[(16 * jjb + l15) * 264 + k0] = pw;
            }
        }
        BAR_LDS();   // bar2: h2s ready

        // ---- phase C: score2 = H2 @ w3q; combine with fp32 S1
        f32x4 acc2 = {};
        const int rowc = (16 * w + l15) * 264;
#pragma unroll
        for (int s = 0; s < 8; ++s) {
            const s16x8 a2 = *(const s16x8*)&h2s[rowc + 32 * s + 8 * lg];
            const s16x8 wq = *(const s16x8*)&w3qf[(s * 64 + l) * 8];
            acc2 = __builtin_amdgcn_mfma_f32_16x16x32_bf16(a2, wq, acc2, 0, 0, 0);
        }
        if (l15 < 8) {
            float4 sc;
            sc.x = (acc2[0] + s1v.x) * SCALE_INV;
            sc.y = (acc2[1] + s1v.y) * SCALE_INV;
            sc.z = (acc2[2] + s1v.z) * SCALE_INV;
            sc.w = (acc2[3] + s1v.w) * SCALE_INV;
            *(float4*)&slds[l15 * 68 + 16 * w + 4 * lg] = sc;
        }
        BAR_LDS();   // bar3: slds scores ready

        // ---- p-gen (wave w owns heads 2w, 2w+1) + PV, wave-local only
        {
            const int h0 = 2 * w, h1 = 2 * w + 1;
            const float s0 = slds[h0 * 68 + l];
            const float s1 = slds[h1 * 68 + l];
            float m0 = s0, m1 = s1;
#pragma unroll
            for (int o = 1; o < 64; o <<= 1) {
                m0 = fmaxf(m0, __shfl_xor(m0, o));
                m1 = fmaxf(m1, __shfl_xor(m1, o));
            }
            const float nm0 = fmaxf(mr0, m0), nm1 = fmaxf(mr1, m1);
            const float r0 = __expf(mr0 - nm0), r1 = __expf(mr1 - nm1);
            mr0 = nm0; mr1 = nm1;
            const float p0 = __expf(s0 - nm0), p1 = __expf(s1 - nm1);
            psum0 = psum0 * r0 + p0;
            psum1 = psum1 * r1 + p1;
            slds[h0 * 68 + l] = p0;
            slds[h1 * 68 + l] = p1;
            asm volatile("s_waitcnt lgkmcnt(0)" ::: "memory");  // own-wave LDS fence
            pv *= (l < 32) ? r0 : r1;
            const float* vp = Vt + (size_t)t * N + j0;
            const float* pp = &slds[h * 68];
#pragma unroll
            for (int cc = 0; cc < 4; ++cc) {
                const float4 v0 = *(const float4*)(vp + 16 * cc);
                const float4 v1 = *(const float4*)(vp + 16 * cc + 4);
                const float4 v2 = *(const float4*)(vp + 16 * cc + 8);
                const float4 v3 = *(const float4*)(vp + 16 * cc + 12);
                const float4 pa = *(const float4*)(pp + 16 * cc);
                const float4 pb = *(const float4*)(pp + 16 * cc + 4);
                const float4 pc = *(const float4*)(pp + 16 * cc + 8);
                const float4 pd = *(const float4*)(pp + 16 * cc + 12);
                pv += pa.x * v0.x + pa.y * v0.y + pa.z * v0.z + pa.w * v0.w
                    + pb.x * v1.x + pb.y * v1.y + pb.z * v1.z + pb.w * v1.w
                    + pc.x * v2.x + pc.y * v2.y + pc.z * v2.z + pc.w * v2.w
                    + pd.x * v3.x + pd.y * v3.y + pd.z * v3.z + pd.w * v3.w;
            }
        }
        // no end-of-tile barrier: all cross-wave hazards are >=1 barrier away
    }

    // ---------------- epilogue: psum reduce, normalize, Wo projection
#pragma unroll
    for (int o = 1; o < 64; o <<= 1) {
        psum0 += __shfl_xor(psum0, o);
        psum1 += __shfl_xor(psum1, o);
    }
    const float denom = (l < 32) ? psum0 : psum1;
    __syncthreads();       // all PV reads of slds done before overlay
    oa[t] = pv / denom;
    __syncthreads();
    float r = bo[t];
    const float* wop = WoT + (size_t)t * HID;
#pragma unroll 4
    for (int k = 0; k < HID; k += 4) {
        const float4 ov = *(const float4*)&oa[k];
        const float4 wv = *(const float4*)(wop + k);
        r += ov.x * wv.x + ov.y * wv.y + ov.z * wv.z + ov.w * wv.w;
    }
    out[(size_t)i * HID + t] = r;
}

// ---------------------------------------------------------------------------
extern "C" void kernel_launch(void* const* d_in, const int* in_sizes, int n_in,
                              void* d_out, int out_size, void* d_ws, size_t ws_size,
                              hipStream_t stream)
{
    const float* x   = (const float*)d_in[0];
    const float* pos = (const float*)d_in[1];
    const float* Wq  = (const float*)d_in[2];
    const float* bq  = (const float*)d_in[3];
    const float* Wk  = (const float*)d_in[4];
    const float* bk  = (const float*)d_in[5];
    const float* Wv  = (const float*)d_in[6];
    const float* bv  = (const float*)d_in[7];
    const float* Wo  = (const float*)d_in[8];
    const float* bo  = (const float*)d_in[9];
    const float* W1  = (const float*)d_in[10];
    const float* b1  = (const float*)d_in[11];
    const float* W2  = (const float*)d_in[12];
    const float* b2  = (const float*)d_in[13];
    const float* W3  = (const float*)d_in[14];
    const float* b3  = (const float*)d_in[15];  // softmax-invariant, folded out
    (void)b3;
    float* out = (float*)d_out;

    char* ws = (char*)d_ws;
    float* Q  = (float*)(ws + 0);                            // 768*256 f32
    float* A  = (float*)(ws + 786432);                       // 768*256 f32
    float* Kt = (float*)(ws + 1572864);                      // 256*768 f32
    float* Vt = (float*)(ws + 2359296);                      // 256*768 f32
    float* S1 = (float*)(ws + 3145728);                      // 8*768*768 f32
    unsigned short* w2tf = (unsigned short*)(ws + 22020096); // 65536 bf16
    unsigned short* w3qg = (unsigned short*)(ws + 22151168); // 768*4096 bf16
    float* WoT = (float*)(ws + 28442624);                    // 256*256 f32

    prep_kernel<<<1024, 256, 0, stream>>>(x, pos, Wq, bq, Wk, bk, Wv, bv,
                                          W1, W2, W3, Wo,
                                          Q, Kt, Vt, A, w2tf, WoT, w3qg);
    s1_kernel<<<288, 256, 0, stream>>>(Q, Kt, S1);
    fused_main_kernel<<<N, 256, 0, stream>>>(A, S1, Vt, w2tf, w3qg,
                                             b1, b2, WoT, bo, out);
}